// Round 5
// baseline (808.787 us; speedup 1.0000x reference)
//
#include <hip/hip_runtime.h>
#include <hip/hip_bf16.h>

typedef float f32x4 __attribute__((ext_vector_type(4)));

// Problem: B=8, C=256, H=W=256, P=16 -> h=w=16, 256 patches + 1 global row.
// ws layout (floats):
//   w1t:  [0,      65536)   transposed w1 (c-major)
//   w2t:  [65536, 131072)   transposed w2
//   mix:  [131072, 657408)  (B*257*256) mix[b][n][c]
//   m2 :  [657408, 1183744) (B*257*256) second-layer activations
//   att:  [1183744, 1185792) (B*256) softmax attention
//   cnt:  [1185792)          grid-barrier counter (zeroed via hipMemsetAsync)
#define WS_W1T 0
#define WS_W2T 65536
#define WS_MIX 131072
#define WS_M2  657408
#define WS_ATT 1183744
#define WS_CNT 1185792

// ---- manual grid barrier: monotonic counter, agent scope, no reset race ----
__device__ __forceinline__ void grid_bar(unsigned* cnt, unsigned target) {
    __syncthreads();
    if (threadIdx.x == 0) {
        __threadfence();  // release prior global writes (agent scope)
        __hip_atomic_fetch_add(cnt, 1u, __ATOMIC_ACQ_REL, __HIP_MEMORY_SCOPE_AGENT);
        while (__hip_atomic_load(cnt, __ATOMIC_ACQUIRE, __HIP_MEMORY_SCOPE_AGENT) < target) {
            __builtin_amdgcn_s_sleep(2);
        }
        __threadfence();  // acquire side
    }
    __syncthreads();
}

// ---- phase A worker: patch means + global mean for one (b,c) plane ----
__device__ __forceinline__ void do_plane_means(const float* __restrict__ x,
                                               float* __restrict__ mix,
                                               int plane, int t, float* smem) {
    int lane = t & 63, wid = t >> 6;
    int pcol = lane >> 2;
    float (*bins)[16] = (float (*)[16])smem;   // 16x16
    float* wsum = smem + 256;                  // 4
    int b = plane >> 8, c = plane & 255;
    const f32x4* wp = (const f32x4*)x + (size_t)plane * 16384
                      + (size_t)wid * 4096 + lane;
    for (int band = 0; band < 4; ++band) {
        float acc = 0.f;
        #pragma unroll
        for (int r = 0; r < 16; ++r) {
            f32x4 v = __builtin_nontemporal_load(wp + (band * 16 + r) * 64);
            acc += v.x + v.y + v.z + v.w;
        }
        acc += __shfl_xor(acc, 1);
        acc += __shfl_xor(acc, 2);
        if ((lane & 3) == 0) bins[wid * 4 + band][pcol] = acc;
    }
    __syncthreads();
    float pm = bins[t >> 4][t & 15] * (1.0f / 256.0f);
    mix[((size_t)b * 257 + t) * 256 + c] = pm;
    float s = pm;
    for (int off = 1; off < 64; off <<= 1) s += __shfl_xor(s, off);
    if (lane == 0) wsum[wid] = s;
    __syncthreads();
    if (t == 0)
        mix[((size_t)b * 257 + 256) * 256 + c] =
            (wsum[0] + wsum[1] + wsum[2] + wsum[3]) * (1.0f / 256.0f);
    __syncthreads();   // smem reused by next iteration/phase
}

// ---- phase B worker: fused 2-layer MLP for 4 rows ----
__device__ __forceinline__ void do_mlp4(const float* __restrict__ mix,
                                        const float* __restrict__ w1t,
                                        const float* __restrict__ b1,
                                        const float* __restrict__ w2t,
                                        const float* __restrict__ b2,
                                        float* __restrict__ m2,
                                        int r0, int o, float* smem) {
    float (*in)[256]  = (float (*)[256])smem;          // 4x256
    float (*mid)[256] = (float (*)[256])(smem + 1024); // 4x256
    #pragma unroll
    for (int j = 0; j < 4; ++j) in[j][o] = mix[(size_t)(r0 + j) * 256 + o];
    __syncthreads();
    float acc[4];
    float bb = b1[o];
    #pragma unroll
    for (int j = 0; j < 4; ++j) acc[j] = bb;
    #pragma unroll 4
    for (int c = 0; c < 256; ++c) {
        float wv = w1t[c * 256 + o];
        #pragma unroll
        for (int j = 0; j < 4; ++j) acc[j] = fmaf(in[j][c], wv, acc[j]);
    }
    #pragma unroll
    for (int j = 0; j < 4; ++j) mid[j][o] = fmaxf(acc[j], 0.f);
    __syncthreads();
    float bb2 = b2[o];
    #pragma unroll
    for (int j = 0; j < 4; ++j) acc[j] = bb2;
    #pragma unroll 4
    for (int c = 0; c < 256; ++c) {
        float wv = w2t[c * 256 + o];
        #pragma unroll
        for (int j = 0; j < 4; ++j) acc[j] = fmaf(mid[j][c], wv, acc[j]);
    }
    #pragma unroll
    for (int j = 0; j < 4; ++j)
        m2[(size_t)(r0 + j) * 256 + o] = fmaxf(acc[j], 0.f);
    __syncthreads();
}

// ---- phase C worker: scores + softmax for one batch (256 threads) ----
__device__ __forceinline__ void do_softmax(const float* __restrict__ m2,
                                           float* __restrict__ att,
                                           int b, int t, float* smem) {
    const float* base = m2 + (size_t)b * 257 * 256;
    int lane = t & 63, wid = t >> 6;
    float* gf2    = smem;        // 256
    float* scores = smem + 256;  // 256
    float* redm   = smem + 512;  // 4
    float* reds   = smem + 516;  // 4
    gf2[t] = base[65536 + t];
    __syncthreads();
    f32x4 gv = ((const f32x4*)gf2)[lane];
    for (int r = 0; r < 64; ++r) {
        int n = wid * 64 + r;
        f32x4 v = ((const f32x4*)(base + (size_t)n * 256))[lane];
        float s = v.x * gv.x + v.y * gv.y + v.z * gv.z + v.w * gv.w;
        #pragma unroll
        for (int off = 1; off < 64; off <<= 1) s += __shfl_xor(s, off);
        if (lane == 0) scores[n] = s;
    }
    __syncthreads();
    float s = scores[t];
    float m = s;
    #pragma unroll
    for (int off = 1; off < 64; off <<= 1) m = fmaxf(m, __shfl_xor(m, off));
    if (lane == 0) redm[wid] = m;
    __syncthreads();
    float M = fmaxf(fmaxf(redm[0], redm[1]), fmaxf(redm[2], redm[3]));
    float e = __expf(s - M);
    float sum = e;
    #pragma unroll
    for (int off = 1; off < 64; off <<= 1) sum += __shfl_xor(sum, off);
    if (lane == 0) reds[wid] = sum;
    __syncthreads();
    float S = reds[0] + reds[1] + reds[2] + reds[3];
    att[b * 256 + t] = e / S;
    __syncthreads();
}

// ---- phase D worker: out = x*(1+att) for one plane ----
__device__ __forceinline__ void do_apply_plane(const float* __restrict__ x,
                                               float* __restrict__ out,
                                               const float* __restrict__ att_l,
                                               int plane, int t) {
    const f32x4* xv = (const f32x4*)x + (size_t)plane * 16384;
    f32x4* ov = (f32x4*)out + (size_t)plane * 16384;
    int col4 = t & 63;
    #pragma unroll 4
    for (int prow = 0; prow < 16; ++prow) {
        float a = 1.0f + att_l[(prow << 4) | (col4 >> 2)];
        size_t base2 = (size_t)prow * 1024 + t;
        #pragma unroll
        for (int k = 0; k < 4; ++k) {
            size_t i = base2 + (size_t)k * 256;
            f32x4 v = __builtin_nontemporal_load(&xv[i]);
            v.x *= a; v.y *= a; v.z *= a; v.w *= a;
            __builtin_nontemporal_store(v, &ov[i]);
        }
    }
}

// ---- fused persistent kernel, manual grid barriers, grid-stride phases ----
__global__ void __launch_bounds__(256, 4) k_fused(
    const float* __restrict__ x,
    const float* __restrict__ w1, const float* __restrict__ b1,
    const float* __restrict__ w2, const float* __restrict__ b2,
    float* __restrict__ out, float* __restrict__ ws, int NB)
{
    float* w1t = ws + WS_W1T;
    float* w2t = ws + WS_W2T;
    float* mix = ws + WS_MIX;
    float* m2  = ws + WS_M2;
    float* att = ws + WS_ATT;
    unsigned* cnt = (unsigned*)(ws + WS_CNT);

    int blk = blockIdx.x;
    int t = threadIdx.x;
    __shared__ float smem[2064];

    // Phase A0: weight transpose (grid-stride over 131072 elems)
    for (int idx = blk * 256 + t; idx < 131072; idx += NB * 256) {
        int m = idx & 65535;
        int o = m >> 8, c = m & 255;
        if (idx < 65536) w1t[c * 256 + o] = w1[m];
        else             w2t[c * 256 + o] = w2[m];
    }
    // Phase A: patch + global means, one plane per iteration
    for (int plane = blk; plane < 2048; plane += NB)
        do_plane_means(x, mix, plane, t, smem);

    grid_bar(cnt, (unsigned)NB);

    // Phase B: MLP, 4 rows per iteration (514 virtual blocks)
    for (int vb = blk; vb < 514; vb += NB)
        do_mlp4(mix, w1t, b1, w2t, b2, m2, vb * 4, t, smem);

    grid_bar(cnt, (unsigned)(2 * NB));

    // Phase C: softmax per batch (8 virtual blocks)
    for (int vb = blk; vb < 8; vb += NB)
        do_softmax(m2, att, vb, t, smem);

    grid_bar(cnt, (unsigned)(3 * NB));

    // Phase D: apply, one plane per iteration
    float* att_l = smem;
    int cur_b = -1;
    for (int plane = blk; plane < 2048; plane += NB) {
        int b = plane >> 8;
        if (b != cur_b) {
            __syncthreads();
            att_l[t] = att[b * 256 + t];
            __syncthreads();
            cur_b = b;
        }
        do_apply_plane(x, out, att_l, plane, t);
    }
}

extern "C" void kernel_launch(void* const* d_in, const int* in_sizes, int n_in,
                              void* d_out, int out_size, void* d_ws, size_t ws_size,
                              hipStream_t stream) {
    const float* x  = (const float*)d_in[0];
    const float* w1 = (const float*)d_in[1];
    const float* b1 = (const float*)d_in[2];
    const float* w2 = (const float*)d_in[3];
    const float* b2 = (const float*)d_in[4];
    float* out = (float*)d_out;
    float* ws  = (float*)d_ws;

    // Co-residency: same oracle cooperative launch uses; grid-stride loops
    // make any NB correct. Computed fresh each call (deterministic).
    int perCU = 0;
    hipError_t e = hipOccupancyMaxActiveBlocksPerMultiprocessor(
        &perCU, (const void*)k_fused, 256, 0);
    if (e != hipSuccess || perCU < 1) perCU = 1;
    int NB = perCU * 256;
    if (NB > 2048) NB = 2048;

    // Zero the barrier counter (capturable stream op; no cross-call state).
    hipMemsetAsync(ws + WS_CNT, 0, 64, stream);

    k_fused<<<NB, 256, 0, stream>>>(x, w1, b1, w2, b2, out, ws, NB);
}

// Round 6
// 543.374 us; speedup vs baseline: 1.4885x; 1.4885x over previous
//
#include <hip/hip_runtime.h>
#include <hip/hip_bf16.h>

typedef float f32x4 __attribute__((ext_vector_type(4)));

// Problem: B=8, C=256, H=W=256, P=16 -> h=w=16, 256 patches + 1 global row.
// ws layout (floats):
//   w1t:  [0,      65536)   transposed w1 (c-major)
//   w2t:  [65536, 131072)   transposed w2
//   mix:  [131072, 657408)  (B*257*256) mix[b][n][c]
//   m2 :  [657408, 1183744) (B*257*256) second-layer activations
//   att:  [1183744, 1185792) (B*256) softmax attention
//   cnt:  [1185792)          grid-barrier counter (zeroed via hipMemsetAsync)
#define WS_W1T 0
#define WS_W2T 65536
#define WS_MIX 131072
#define WS_M2  657408
#define WS_ATT 1183744
#define WS_CNT 1185792

// ---- manual grid barrier: monotonic counter, RELAXED backoff spin ----
// R5 lesson: un-throttled agent-scope ACQUIRE polling from 2048 blocks
// hammered one line (cross-XCD) and starved the memory pipe (571 GB/s).
// Fix: relaxed polls with s_sleep backoff; one acquire fence at exit.
__device__ __forceinline__ void grid_bar(unsigned* cnt, unsigned target) {
    __syncthreads();
    if (threadIdx.x == 0) {
        __threadfence();  // release prior global writes (agent scope)
        __hip_atomic_fetch_add(cnt, 1u, __ATOMIC_RELEASE, __HIP_MEMORY_SCOPE_AGENT);
        int spins = 0;
        while (__hip_atomic_load(cnt, __ATOMIC_RELAXED, __HIP_MEMORY_SCOPE_AGENT) < target) {
            if (spins < 8) { __builtin_amdgcn_s_sleep(1); ++spins; }
            else           { __builtin_amdgcn_s_sleep(127); }   // ~3.4 us/poll
        }
        __threadfence();  // acquire side
    }
    __syncthreads();
}

// ---- phase A worker: patch means + global mean for one (b,c) plane ----
__device__ __forceinline__ void do_plane_means(const float* __restrict__ x,
                                               float* __restrict__ mix,
                                               int plane, int t, float* smem) {
    int lane = t & 63, wid = t >> 6;
    int pcol = lane >> 2;
    float (*bins)[16] = (float (*)[16])smem;   // 16x16
    float* wsum = smem + 256;                  // 4
    int b = plane >> 8, c = plane & 255;
    const f32x4* wp = (const f32x4*)x + (size_t)plane * 16384
                      + (size_t)wid * 4096 + lane;
    for (int band = 0; band < 4; ++band) {
        float acc = 0.f;
        #pragma unroll
        for (int r = 0; r < 16; ++r) {
            f32x4 v = __builtin_nontemporal_load(wp + (band * 16 + r) * 64);
            acc += v.x + v.y + v.z + v.w;
        }
        acc += __shfl_xor(acc, 1);
        acc += __shfl_xor(acc, 2);
        if ((lane & 3) == 0) bins[wid * 4 + band][pcol] = acc;
    }
    __syncthreads();
    float pm = bins[t >> 4][t & 15] * (1.0f / 256.0f);
    mix[((size_t)b * 257 + t) * 256 + c] = pm;
    float s = pm;
    for (int off = 1; off < 64; off <<= 1) s += __shfl_xor(s, off);
    if (lane == 0) wsum[wid] = s;
    __syncthreads();
    if (t == 0)
        mix[((size_t)b * 257 + 256) * 256 + c] =
            (wsum[0] + wsum[1] + wsum[2] + wsum[3]) * (1.0f / 256.0f);
    __syncthreads();   // smem reused by next iteration/phase
}

// ---- phase B worker: fused 2-layer MLP for 4 rows ----
__device__ __forceinline__ void do_mlp4(const float* __restrict__ mix,
                                        const float* __restrict__ w1t,
                                        const float* __restrict__ b1,
                                        const float* __restrict__ w2t,
                                        const float* __restrict__ b2,
                                        float* __restrict__ m2,
                                        int r0, int o, float* smem) {
    float (*in)[256]  = (float (*)[256])smem;          // 4x256
    float (*mid)[256] = (float (*)[256])(smem + 1024); // 4x256
    #pragma unroll
    for (int j = 0; j < 4; ++j) in[j][o] = mix[(size_t)(r0 + j) * 256 + o];
    __syncthreads();
    float acc[4];
    float bb = b1[o];
    #pragma unroll
    for (int j = 0; j < 4; ++j) acc[j] = bb;
    #pragma unroll 4
    for (int c = 0; c < 256; ++c) {
        float wv = w1t[c * 256 + o];
        #pragma unroll
        for (int j = 0; j < 4; ++j) acc[j] = fmaf(in[j][c], wv, acc[j]);
    }
    #pragma unroll
    for (int j = 0; j < 4; ++j) mid[j][o] = fmaxf(acc[j], 0.f);
    __syncthreads();
    float bb2 = b2[o];
    #pragma unroll
    for (int j = 0; j < 4; ++j) acc[j] = bb2;
    #pragma unroll 4
    for (int c = 0; c < 256; ++c) {
        float wv = w2t[c * 256 + o];
        #pragma unroll
        for (int j = 0; j < 4; ++j) acc[j] = fmaf(mid[j][c], wv, acc[j]);
    }
    #pragma unroll
    for (int j = 0; j < 4; ++j)
        m2[(size_t)(r0 + j) * 256 + o] = fmaxf(acc[j], 0.f);
    __syncthreads();
}

// ---- phase C worker: scores + softmax for one batch (256 threads) ----
__device__ __forceinline__ void do_softmax(const float* __restrict__ m2,
                                           float* __restrict__ att,
                                           int b, int t, float* smem) {
    const float* base = m2 + (size_t)b * 257 * 256;
    int lane = t & 63, wid = t >> 6;
    float* gf2    = smem;        // 256
    float* scores = smem + 256;  // 256
    float* redm   = smem + 512;  // 4
    float* reds   = smem + 516;  // 4
    gf2[t] = base[65536 + t];
    __syncthreads();
    f32x4 gv = ((const f32x4*)gf2)[lane];
    for (int r = 0; r < 64; ++r) {
        int n = wid * 64 + r;
        f32x4 v = ((const f32x4*)(base + (size_t)n * 256))[lane];
        float s = v.x * gv.x + v.y * gv.y + v.z * gv.z + v.w * gv.w;
        #pragma unroll
        for (int off = 1; off < 64; off <<= 1) s += __shfl_xor(s, off);
        if (lane == 0) scores[n] = s;
    }
    __syncthreads();
    float s = scores[t];
    float m = s;
    #pragma unroll
    for (int off = 1; off < 64; off <<= 1) m = fmaxf(m, __shfl_xor(m, off));
    if (lane == 0) redm[wid] = m;
    __syncthreads();
    float M = fmaxf(fmaxf(redm[0], redm[1]), fmaxf(redm[2], redm[3]));
    float e = __expf(s - M);
    float sum = e;
    #pragma unroll
    for (int off = 1; off < 64; off <<= 1) sum += __shfl_xor(sum, off);
    if (lane == 0) reds[wid] = sum;
    __syncthreads();
    float S = reds[0] + reds[1] + reds[2] + reds[3];
    att[b * 256 + t] = e / S;
    __syncthreads();
}

// ---- phase D worker: out = x*(1+att) for one plane ----
__device__ __forceinline__ void do_apply_plane(const float* __restrict__ x,
                                               float* __restrict__ out,
                                               const float* __restrict__ att_l,
                                               int plane, int t) {
    const f32x4* xv = (const f32x4*)x + (size_t)plane * 16384;
    f32x4* ov = (f32x4*)out + (size_t)plane * 16384;
    int col4 = t & 63;
    #pragma unroll 4
    for (int prow = 0; prow < 16; ++prow) {
        float a = 1.0f + att_l[(prow << 4) | (col4 >> 2)];
        size_t base2 = (size_t)prow * 1024 + t;
        #pragma unroll
        for (int k = 0; k < 4; ++k) {
            size_t i = base2 + (size_t)k * 256;
            f32x4 v = __builtin_nontemporal_load(&xv[i]);
            v.x *= a; v.y *= a; v.z *= a; v.w *= a;
            __builtin_nontemporal_store(v, &ov[i]);
        }
    }
}

// ---- fused persistent kernel, manual grid barriers, grid-stride phases ----
__global__ void __launch_bounds__(256, 4) k_fused(
    const float* __restrict__ x,
    const float* __restrict__ w1, const float* __restrict__ b1,
    const float* __restrict__ w2, const float* __restrict__ b2,
    float* __restrict__ out, float* __restrict__ ws, int NB)
{
    float* w1t = ws + WS_W1T;
    float* w2t = ws + WS_W2T;
    float* mix = ws + WS_MIX;
    float* m2  = ws + WS_M2;
    float* att = ws + WS_ATT;
    unsigned* cnt = (unsigned*)(ws + WS_CNT);

    int blk = blockIdx.x;
    int t = threadIdx.x;
    __shared__ float smem[2064];

    // Phase A0: weight transpose (grid-stride over 131072 elems)
    for (int idx = blk * 256 + t; idx < 131072; idx += NB * 256) {
        int m = idx & 65535;
        int o = m >> 8, c = m & 255;
        if (idx < 65536) w1t[c * 256 + o] = w1[m];
        else             w2t[c * 256 + o] = w2[m];
    }
    // Phase A: patch + global means, one plane per iteration
    for (int plane = blk; plane < 2048; plane += NB)
        do_plane_means(x, mix, plane, t, smem);

    grid_bar(cnt, (unsigned)NB);

    // Phase B: MLP, 4 rows per iteration (514 virtual blocks)
    for (int vb = blk; vb < 514; vb += NB)
        do_mlp4(mix, w1t, b1, w2t, b2, m2, vb * 4, t, smem);

    grid_bar(cnt, (unsigned)(2 * NB));

    // Phase C: softmax per batch (8 virtual blocks)
    for (int vb = blk; vb < 8; vb += NB)
        do_softmax(m2, att, vb, t, smem);

    grid_bar(cnt, (unsigned)(3 * NB));

    // Phase D: apply, one plane per iteration
    float* att_l = smem;
    int cur_b = -1;
    for (int plane = blk; plane < 2048; plane += NB) {
        int b = plane >> 8;
        if (b != cur_b) {
            __syncthreads();
            att_l[t] = att[b * 256 + t];
            __syncthreads();
            cur_b = b;
        }
        do_apply_plane(x, out, att_l, plane, t);
    }
}

extern "C" void kernel_launch(void* const* d_in, const int* in_sizes, int n_in,
                              void* d_out, int out_size, void* d_ws, size_t ws_size,
                              hipStream_t stream) {
    const float* x  = (const float*)d_in[0];
    const float* w1 = (const float*)d_in[1];
    const float* b1 = (const float*)d_in[2];
    const float* w2 = (const float*)d_in[3];
    const float* b2 = (const float*)d_in[4];
    float* out = (float*)d_out;
    float* ws  = (float*)d_ws;

    // Co-residency via occupancy oracle; grid-stride loops make any NB correct.
    int perCU = 0;
    hipError_t e = hipOccupancyMaxActiveBlocksPerMultiprocessor(
        &perCU, (const void*)k_fused, 256, 0);
    if (e != hipSuccess || perCU < 1) perCU = 1;
    int NB = perCU * 256;
    if (NB > 2048) NB = 2048;

    // Zero the barrier counter (capturable stream op; no cross-call state).
    hipMemsetAsync(ws + WS_CNT, 0, 64, stream);

    k_fused<<<NB, 256, 0, stream>>>(x, w1, b1, w2, b2, out, ws, NB);
}

// Round 7
// 331.781 us; speedup vs baseline: 2.4377x; 1.6377x over previous
//
#include <hip/hip_runtime.h>
#include <hip/hip_bf16.h>

typedef float f32x4 __attribute__((ext_vector_type(4)));

// Problem: B=8, C=256, H=W=256, P=16 -> h=w=16, 256 patches + 1 global row.
// R6: reverted from persistent-kernel fusion (flat grid barrier = 100-200us
// per barrier from cross-XCD same-line RMW serialization; R5/R6 evidence).
// Multi-kernel pipeline, R2-verified math, minus the weight transpose.
//
// ws layout (floats):
//   mix:  [0,      526336)   (B*257*256) mix[b][n][c]
//   m2 :  [526336, 1052672)  (B*257*256) second-layer activations
//   att:  [1052672, 1054720) (B*256) softmax attention
#define WS_MIX 0
#define WS_M2  526336
#define WS_ATT 1052672

// ---------------- K1: per-plane patch means + global mean ----------------
// One block (256 thr) per (b,c) plane of 256x256 floats.
// Wave wid owns rows [64*wid, 64*wid+64) = patch-rows [4*wid, 4*wid+4).
__global__ void k_patch_means(const float* __restrict__ x,
                              float* __restrict__ mix) {
    int plane = blockIdx.x;           // b*256 + c
    int b = plane >> 8, c = plane & 255;
    const f32x4* p = (const f32x4*)x + (size_t)plane * 16384;
    int t = threadIdx.x;
    int lane = t & 63, wid = t >> 6;
    int pcol = lane >> 2;             // patch column this 4-lane group feeds

    __shared__ float bins[16][16];

    const f32x4* wp = p + (size_t)wid * 4096 + lane;  // wave's first row
    for (int band = 0; band < 4; ++band) {
        float acc = 0.f;
        #pragma unroll
        for (int r = 0; r < 16; ++r) {
            f32x4 v = __builtin_nontemporal_load(wp + (band * 16 + r) * 64);
            acc += v.x + v.y + v.z + v.w;
        }
        acc += __shfl_xor(acc, 1);
        acc += __shfl_xor(acc, 2);
        if ((lane & 3) == 0) bins[wid * 4 + band][pcol] = acc;
    }
    __syncthreads();

    // thread t owns patch n = t
    float pm = bins[t >> 4][t & 15] * (1.0f / 256.0f);  // patch mean
    mix[((size_t)b * 257 + t) * 256 + c] = pm;

    // global mean = mean of patch means (equal-sized patches)
    float s = pm;
    for (int off = 1; off < 64; off <<= 1) s += __shfl_xor(s, off);
    __shared__ float wsum[4];
    if (lane == 0) wsum[wid] = s;
    __syncthreads();
    if (t == 0) {
        float g = (wsum[0] + wsum[1] + wsum[2] + wsum[3]) * (1.0f / 256.0f);
        mix[((size_t)b * 257 + 256) * 256 + c] = g;
    }
}

// ---------------- K2a: fused 2-layer MLP, 4 rows per block ----------------
// No weight transpose: thread o reads w-row o sequentially as f32x4
// (per-thread-sequential; weights are L2-resident at 512 KiB total).
__global__ void k_mlp(const float* __restrict__ mix,
                      const float* __restrict__ w1, const float* __restrict__ b1,
                      const float* __restrict__ w2, const float* __restrict__ b2,
                      float* __restrict__ m2out) {
    int r0 = blockIdx.x * 4;  // 514 blocks * 4 = 2056 rows
    int o = threadIdx.x;

    __shared__ float in[4][256];
    __shared__ float mid[4][256];
    #pragma unroll
    for (int j = 0; j < 4; ++j) in[j][o] = mix[(size_t)(r0 + j) * 256 + o];
    __syncthreads();

    const f32x4* w1r = (const f32x4*)(w1 + o * 256);
    float acc[4];
    float bb = b1[o];
    #pragma unroll
    for (int j = 0; j < 4; ++j) acc[j] = bb;
    #pragma unroll 8
    for (int c4 = 0; c4 < 64; ++c4) {
        f32x4 wv = w1r[c4];
        #pragma unroll
        for (int j = 0; j < 4; ++j) {
            acc[j] = fmaf(in[j][c4 * 4 + 0], wv.x, acc[j]);
            acc[j] = fmaf(in[j][c4 * 4 + 1], wv.y, acc[j]);
            acc[j] = fmaf(in[j][c4 * 4 + 2], wv.z, acc[j]);
            acc[j] = fmaf(in[j][c4 * 4 + 3], wv.w, acc[j]);
        }
    }
    #pragma unroll
    for (int j = 0; j < 4; ++j) mid[j][o] = fmaxf(acc[j], 0.f);
    __syncthreads();

    const f32x4* w2r = (const f32x4*)(w2 + o * 256);
    float bb2 = b2[o];
    #pragma unroll
    for (int j = 0; j < 4; ++j) acc[j] = bb2;
    #pragma unroll 8
    for (int c4 = 0; c4 < 64; ++c4) {
        f32x4 wv = w2r[c4];
        #pragma unroll
        for (int j = 0; j < 4; ++j) {
            acc[j] = fmaf(mid[j][c4 * 4 + 0], wv.x, acc[j]);
            acc[j] = fmaf(mid[j][c4 * 4 + 1], wv.y, acc[j]);
            acc[j] = fmaf(mid[j][c4 * 4 + 2], wv.z, acc[j]);
            acc[j] = fmaf(mid[j][c4 * 4 + 3], wv.w, acc[j]);
        }
    }
    #pragma unroll
    for (int j = 0; j < 4; ++j)
        m2out[(size_t)(r0 + j) * 256 + o] = fmaxf(acc[j], 0.f);
}

// ---------------- K2b: scores + softmax per batch ----------------
// 1024 threads = 16 waves; each wave dots 16 rows (float4-coalesced),
// then threads 0..255 do the block softmax.
__global__ void k_softmax(const float* __restrict__ m2,
                          float* __restrict__ att) {
    int b = blockIdx.x;
    const float* base = m2 + (size_t)b * 257 * 256;
    int t = threadIdx.x;          // 0..1023
    int lane = t & 63, w = t >> 6;

    __shared__ float gf2[256];
    __shared__ float scores[256];
    if (t < 256) gf2[t] = base[65536 + t];
    __syncthreads();

    f32x4 gv = ((const f32x4*)gf2)[lane];
    for (int r = 0; r < 16; ++r) {
        int n = w * 16 + r;
        f32x4 v = ((const f32x4*)(base + (size_t)n * 256))[lane];
        float s = v.x * gv.x + v.y * gv.y + v.z * gv.z + v.w * gv.w;
        #pragma unroll
        for (int off = 1; off < 64; off <<= 1) s += __shfl_xor(s, off);
        if (lane == 0) scores[n] = s;
    }
    __syncthreads();

    float s = (t < 256) ? scores[t] : -1e30f;
    float m = s;
    #pragma unroll
    for (int off = 1; off < 64; off <<= 1) m = fmaxf(m, __shfl_xor(m, off));
    __shared__ float redm[16];
    if (lane == 0) redm[w] = m;
    __syncthreads();
    float M = fmaxf(fmaxf(redm[0], redm[1]), fmaxf(redm[2], redm[3]));

    float e = (t < 256) ? __expf(s - M) : 0.f;
    float sum = e;
    #pragma unroll
    for (int off = 1; off < 64; off <<= 1) sum += __shfl_xor(sum, off);
    __shared__ float reds[16];
    if (lane == 0) reds[w] = sum;
    __syncthreads();
    float S = reds[0] + reds[1] + reds[2] + reds[3];

    if (t < 256) att[b * 256 + t] = e / S;
}

// ---------------- K3: out = x * (1 + att_up) ----------------
// One block per 16-row patch band of one plane: blk>>4 = plane, blk&15 = band.
// att scalar is loop-invariant per thread. Nontemporal both ways (pure sweep).
__global__ void k_apply(const float* __restrict__ x,
                        const float* __restrict__ att,
                        float* __restrict__ out) {
    const f32x4* xv = (const f32x4*)x;
    f32x4* ov = (f32x4*)out;
    int blk = blockIdx.x;
    int b = blk >> 12;                 // plane>>8
    int prow = blk & 15;
    int col4 = threadIdx.x & 63;
    int patch = (prow << 4) | (col4 >> 2);
    float a = 1.0f + att[(b << 8) + patch];

    size_t base = (size_t)blk * 1024 + threadIdx.x;
    #pragma unroll
    for (int k = 0; k < 4; ++k) {
        size_t i = base + (size_t)k * 256;
        f32x4 v = __builtin_nontemporal_load(&xv[i]);
        v.x *= a; v.y *= a; v.z *= a; v.w *= a;
        __builtin_nontemporal_store(v, &ov[i]);
    }
}

extern "C" void kernel_launch(void* const* d_in, const int* in_sizes, int n_in,
                              void* d_out, int out_size, void* d_ws, size_t ws_size,
                              hipStream_t stream) {
    const float* x  = (const float*)d_in[0];
    const float* w1 = (const float*)d_in[1];
    const float* b1 = (const float*)d_in[2];
    const float* w2 = (const float*)d_in[3];
    const float* b2 = (const float*)d_in[4];
    float* out = (float*)d_out;
    float* ws  = (float*)d_ws;

    float* mix = ws + WS_MIX;
    float* m2  = ws + WS_M2;
    float* att = ws + WS_ATT;

    // K1: patch + global means (one block per (b,c) plane)
    k_patch_means<<<8 * 256, 256, 0, stream>>>(x, mix);
    // K2a: MLP over all 8*257 rows, 4 rows per block, direct weight rows
    k_mlp<<<(8 * 257) / 4, 256, 0, stream>>>(mix, w1, b1, w2, b2, m2);
    // K2b: scores + softmax
    k_softmax<<<8, 1024, 0, stream>>>(m2, att);
    // K3: 32768 blocks, one patch band each
    k_apply<<<32768, 256, 0, stream>>>(x, att, out);
}